// Round 2
// baseline (5028.211 us; speedup 1.0000x reference)
//
#include <hip/hip_runtime.h>
#include <math.h>

// CollapseEngine, round 2: bf16x3 split-precision MFMA, fully fused.
// h-state register-resident (batch on lanes via transposed GEMM), W pre-split
// + pre-fragment-ordered in d_ws, LDS only for W chunks (double-buffered
// global_load_lds) + reordered anchors/biases.
//
// GEMM math (per layer):  t^T = tanh(W1 h^T + b1),  h' = clip(h + W2 t^T + b2 + force)
// MFMA 32x32x16 bf16, D rows = n-features (from A=W frags), D cols = batch (lane&31).
// Split: x = hi(trunc bf16) + lo(rne bf16); D = Ah*Bh + Ah*Bl + Al*Bh  (~2^-16 rel).

#define DIMX 256
#define NL 6
#define BPW 32          // batch rows per wave (= MFMA tile cols)
#define WVS 8           // waves per block
#define RPB (BPW*WVS)   // 256 batch rows per block

typedef float   f32x16 __attribute__((ext_vector_type(16)));
typedef short   short8 __attribute__((ext_vector_type(8)));
typedef unsigned int u32x4 __attribute__((ext_vector_type(4)));

// ws uint4-granule chunk base: [gemm g][pass][ksp] chunks of 1024 granules (16KB)
#define CHB(g, pass, ksp) ((((g)*2 + (pass))*8 + (ksp)) * 1024)

// component select, const r only (folds under unroll)
#define VC(v, r) ((r)==0 ? (v).x : (r)==1 ? (v).y : (r)==2 ? (v).z : (v).w)

// ---------------- W split + fragment-reorder prologue ----------------
// granule gi: [g(2)][pass(2)][ksp(8)][ks2(2)][ntp(4)][hl(2)][lane(64)] = 32768
// content: 8 bf16 = W[n][k0..k0+7] hi-parts (hl=0) or lo-parts (hl=1)
// n = (pass*4+ntp)*32 + (lane&31), k0 = (ksp*2+ks2)*16 + (lane>>5)*8
__global__ void wsplit(const float* __restrict__ W1, const float* __restrict__ W2,
                       u32x4* __restrict__ ws) {
    int gi = blockIdx.x * 256 + threadIdx.x;        // 0..32767
    int g   = gi >> 14;
    int r   = gi & 16383;
    int pass= r >> 13;
    int ksp = (r >> 10) & 7;
    int ks2 = (r >> 9) & 1;
    int ntp = (r >> 7) & 3;
    int hl  = (r >> 6) & 1;
    int ln  = r & 63;
    int n   = (pass*4 + ntp)*32 + (ln & 31);
    int k0  = (ksp*2 + ks2)*16 + (ln >> 5)*8;
    const float* Wg = g ? W2 : W1;
    const float4 xa = *(const float4*)&Wg[n*DIMX + k0];
    const float4 xb = *(const float4*)&Wg[n*DIMX + k0 + 4];
    float x[8] = {xa.x, xa.y, xa.z, xa.w, xb.x, xb.y, xb.z, xb.w};
    unsigned o[4];
#pragma unroll
    for (int p = 0; p < 4; ++p) {
        float x0 = x[2*p], x1 = x[2*p+1];
        unsigned b0 = __float_as_uint(x0), b1 = __float_as_uint(x1);
        if (hl == 0) {
            // hi-pack: {bf16_trunc(x1), bf16_trunc(x0)}
            o[p] = __builtin_amdgcn_perm(b1, b0, 0x07060302u);
        } else {
            float l0 = x0 - __uint_as_float(b0 & 0xffff0000u);
            float l1 = x1 - __uint_as_float(b1 & 0xffff0000u);
            unsigned lp;
            asm("v_cvt_pk_bf16_f32 %0, %1, %2" : "=v"(lp) : "v"(l0), "v"(l1));
            o[p] = lp;
        }
    }
    u32x4 out = {o[0], o[1], o[2], o[3]};
    ws[gi] = out;
}

// ---------------- main fused kernel ----------------

// stage 2 granule-rows per wave into LDS (linear, global_load_lds width 16)
#define STAGE(gIdxBase, ldsSlotBase)                                             \
    {                                                                            \
        _Pragma("unroll")                                                        \
        for (int i_ = 0; i_ < 2; ++i_) {                                         \
            const int off_ = ((w*2 + i_) << 6);                                  \
            __builtin_amdgcn_global_load_lds(                                    \
                (const __attribute__((address_space(1))) void*)(ws + (gIdxBase) + off_ + lane), \
                (__attribute__((address_space(3))) void*)(&wf[(ldsSlotBase) + off_]),           \
                16, 0, 0);                                                       \
        }                                                                        \
    }

// assemble B-frag (hi,lo) for kstep from packed pairs SRC[base..base+3] (+64 lo)
// via 2+2 permlane32_swap: v0=e0e1, v1=e2e3, v2=e4e5, v3=e6e7
#define ASSEMBLE(SRC, base, BH, BL)                                              \
    {                                                                            \
        auto s0_ = __builtin_amdgcn_permlane32_swap(SRC[(base)+0], SRC[(base)+2], false, false); \
        auto s1_ = __builtin_amdgcn_permlane32_swap(SRC[(base)+1], SRC[(base)+3], false, false); \
        u32x4 th_ = {s0_[0], s1_[0], s0_[1], s1_[1]};                            \
        BH = __builtin_bit_cast(short8, th_);                                    \
        auto t0_ = __builtin_amdgcn_permlane32_swap(SRC[64+(base)+0], SRC[64+(base)+2], false, false); \
        auto t1_ = __builtin_amdgcn_permlane32_swap(SRC[64+(base)+1], SRC[64+(base)+3], false, false); \
        u32x4 tl_ = {t0_[0], t1_[0], t0_[1], t1_[1]};                            \
        BL = __builtin_bit_cast(short8, tl_);                                    \
    }

#define MMAC(ACC, Ah, Al, Bh, Bl)                                                \
    ACC = __builtin_amdgcn_mfma_f32_32x32x16_bf16(Ah, Bh, ACC, 0, 0, 0);         \
    ACC = __builtin_amdgcn_mfma_f32_32x32x16_bf16(Ah, Bl, ACC, 0, 0, 0);         \
    ACC = __builtin_amdgcn_mfma_f32_32x32x16_bf16(Al, Bh, ACC, 0, 0, 0);

// pack f32 pair -> (hi u32, lo u32)
#define PACKPAIR(X0, X1, HI, LO)                                                 \
    {                                                                            \
        unsigned b0_ = __float_as_uint(X0), b1_ = __float_as_uint(X1);           \
        HI = __builtin_amdgcn_perm(b1_, b0_, 0x07060302u);                       \
        float l0_ = (X0) - __uint_as_float(b0_ & 0xffff0000u);                   \
        float l1_ = (X1) - __uint_as_float(b1_ & 0xffff0000u);                   \
        asm("v_cvt_pk_bf16_f32 %0, %1, %2" : "=v"(LO) : "v"(l0_), "v"(l1_));     \
    }

__global__ __launch_bounds__(512, 4)
void collapse_mfma(const float* __restrict__ h0,
                   const float* __restrict__ b1f,
                   const float* __restrict__ b2f,
                   const float* __restrict__ anchors,
                   const u32x4* __restrict__ ws,
                   float* __restrict__ out_h,
                   float* __restrict__ out_align,
                   float* __restrict__ out_div,
                   float* __restrict__ out_tens,
                   int B)
{
    __shared__ __align__(16) u32x4 wf[4096];         // 2 x 32KB W-frag buffers
    __shared__ __align__(16) float an_reg[3][256];   // normalized anchors, reg-layout
    __shared__ __align__(16) float b1_reg[256];
    __shared__ __align__(16) float b2_reg[256];
    __shared__ float an_inv[3];

    const int tid  = threadIdx.x;
    const int w    = tid >> 6;
    const int lane = tid & 63;
    const int hl   = lane >> 5;          // lane half
    const int bl   = lane & 31;          // batch col within wave tile
    const int bglob = blockIdx.x * RPB + w * BPW + bl;

    // anchor inverse norms (waves 0..2)
    if (w < 3) {
        const float4 av = *(const float4*)&anchors[w*DIMX + lane*4];
        float ss = av.x*av.x + av.y*av.y + av.z*av.z + av.w*av.w;
#pragma unroll
        for (int m = 1; m < 64; m <<= 1) ss += __shfl_xor(ss, m, 64);
        if (lane == 0) an_inv[w] = 1.0f / fmaxf(sqrtf(ss), 1e-12f);
    }
    __syncthreads();

    // reorder anchors (normalized) and biases into reg-layout:
    // idx r: hb=r>>7, T=(r>>4)&7, reg=r&15 -> f = T*32 + (reg>>2)*8 + hb*4 + (reg&3)
    {
        int r8 = tid & 255;
        int hb = r8 >> 7, T = (r8 >> 4) & 7, rg = r8 & 15;
        int f = T*32 + (rg >> 2)*8 + hb*4 + (rg & 3);
        if (tid < 256) b1_reg[r8] = b1f[f];
        else           b2_reg[r8] = b2f[f];
#pragma unroll
        for (int k = 0; k < 3; ++k)
            if (tid < 256) an_reg[k][r8] = anchors[k*DIMX + f] * an_inv[k];
    }
    __syncthreads();

    // load h0 fragments: hr[T][reg], f = T*32 + (reg>>2)*8 + hl*4 + (reg&3)
    f32x16 hr[8];
#pragma unroll
    for (int T = 0; T < 8; ++T) {
#pragma unroll
        for (int q = 0; q < 4; ++q) {
            const float4 v = *(const float4*)&h0[(size_t)bglob*DIMX + T*32 + q*8 + hl*4];
            hr[T][q*4+0] = v.x; hr[T][q*4+1] = v.y; hr[T][q*4+2] = v.z; hr[T][q*4+3] = v.w;
        }
    }

    unsigned tpk[128];   // packed t (hi [0..63], lo [64..127])

#pragma unroll 1
    for (int layer = 0; layer < NL; ++layer) {
        // ---------- stats: 7 partial sums over this lane's 128 feats ----------
        float p0=0, p1=0, p2=0, p3=0, p4=0, p5=0, p6=0;
#pragma unroll
        for (int T = 0; T < 8; ++T) {
#pragma unroll
            for (int q = 0; q < 4; ++q) {
                const float4 a0 = *(const float4*)&an_reg[0][hl*128 + T*16 + q*4];
                const float4 a1 = *(const float4*)&an_reg[1][hl*128 + T*16 + q*4];
                const float4 a2 = *(const float4*)&an_reg[2][hl*128 + T*16 + q*4];
#pragma unroll
                for (int r = 0; r < 4; ++r) {
                    float x = hr[T][q*4+r];
                    float A0 = VC(a0,r), A1 = VC(a1,r), A2 = VC(a2,r);
                    p0 += x*x;
                    p1 += x*A0; p2 += x*A1; p3 += x*A2;
                    float e0 = x-A0, e1 = x-A1, e2 = x-A2;
                    p4 += e0*e0; p5 += e1*e1; p6 += e2*e2;
                }
            }
        }
        p0 += __shfl_xor(p0, 32); p1 += __shfl_xor(p1, 32); p2 += __shfl_xor(p2, 32);
        p3 += __shfl_xor(p3, 32); p4 += __shfl_xor(p4, 32); p5 += __shfl_xor(p5, 32);
        p6 += __shfl_xor(p6, 32);
        const float inv_rn = 1.0f / fmaxf(sqrtf(p0), 1e-12f);
        const float al0 = p1*inv_rn, al1 = p2*inv_rn, al2 = p3*inv_rn;
        const float dv0 = 1.0f-al0, dv1 = 1.0f-al1, dv2 = 1.0f-al2;
        const float c0 = -0.10f*dv0 / fmaxf(sqrtf(p4), 1e-12f);
        const float c1 = -0.10f*dv1 / fmaxf(sqrtf(p5), 1e-12f);
        const float c2 = -0.05f*dv2 / fmaxf(sqrtf(p6), 1e-12f);
        if (hl == 0) {
            const long long tb = ((long long)layer*B + bglob)*3;
            out_align[tb+0]=al0; out_align[tb+1]=al1; out_align[tb+2]=al2;
            out_div[tb+0]=dv0;   out_div[tb+1]=dv1;   out_div[tb+2]=dv2;
            out_tens[tb+0]=dv0*dv0; out_tens[tb+1]=dv1*dv1; out_tens[tb+2]=dv2*dv2;
        }

        // ---------- pack ORIGINAL h (B-operand source for G1) ----------
        unsigned hpk[128];
#pragma unroll
        for (int T = 0; T < 8; ++T) {
#pragma unroll
            for (int i = 0; i < 8; ++i) {
                unsigned hi_, lo_;
                PACKPAIR(hr[T][2*i], hr[T][2*i+1], hi_, lo_);
                hpk[T*8+i] = hi_; hpk[64 + T*8+i] = lo_;
            }
        }

        // ---------- transform h in place: h <- h + b2 + force (G2 acc init) ----------
#pragma unroll
        for (int T = 0; T < 8; ++T) {
#pragma unroll
            for (int q = 0; q < 4; ++q) {
                const float4 a0 = *(const float4*)&an_reg[0][hl*128 + T*16 + q*4];
                const float4 a1 = *(const float4*)&an_reg[1][hl*128 + T*16 + q*4];
                const float4 a2 = *(const float4*)&an_reg[2][hl*128 + T*16 + q*4];
                const float4 bq = *(const float4*)&b2_reg[hl*128 + T*16 + q*4];
#pragma unroll
                for (int r = 0; r < 4; ++r) {
                    float x = hr[T][q*4+r];
                    hr[T][q*4+r] = x + VC(bq,r) + c0*(x - VC(a0,r))
                                             + c1*(x - VC(a1,r))
                                             + c2*(x - VC(a2,r));
                }
            }
        }

        // ---------- G1: t^T = W1 h^T, two 4-tile passes ----------
#pragma unroll
        for (int PASS = 0; PASS < 2; ++PASS) {
            f32x16 ac[4];
#pragma unroll
            for (int j = 0; j < 4; ++j) ac[j] = (f32x16)(0.0f);

            STAGE(CHB(0, PASS, 0), 0);
            __syncthreads();
#pragma unroll
            for (int ksp = 0; ksp < 8; ++ksp) {
                const int cur = ksp & 1;
                if (ksp < 7) STAGE(CHB(0, PASS, ksp+1), (cur^1)*2048);
#pragma unroll
                for (int ks2 = 0; ks2 < 2; ++ks2) {
                    short8 Bh, Bl;
                    ASSEMBLE(hpk, ksp*8 + ks2*4, Bh, Bl);
#pragma unroll
                    for (int j = 0; j < 4; ++j) {
                        const int sl = cur*2048 + ks2*512 + j*128 + lane;
                        short8 Ah = *(const short8*)&wf[sl];
                        short8 Al = *(const short8*)&wf[sl + 64];
                        MMAC(ac[j], Ah, Al, Bh, Bl);
                    }
                }
                __syncthreads();
            }
            // tanh + bias, pack into tpk
#pragma unroll
            for (int j = 0; j < 4; ++j) {
                const int nt = PASS*4 + j;
                float tv[16];
#pragma unroll
                for (int q = 0; q < 4; ++q) {
                    const float4 bq = *(const float4*)&b1_reg[hl*128 + nt*16 + q*4];
#pragma unroll
                    for (int r = 0; r < 4; ++r) {
                        float x = ac[j][q*4+r] + VC(bq,r);
                        float e = __expf(2.0f*x);
                        tv[q*4+r] = 1.0f - 2.0f*__builtin_amdgcn_rcpf(e + 1.0f);
                    }
                }
#pragma unroll
                for (int i = 0; i < 8; ++i) {
                    unsigned hi_, lo_;
                    PACKPAIR(tv[2*i], tv[2*i+1], hi_, lo_);
                    tpk[nt*8+i] = hi_; tpk[64 + nt*8+i] = lo_;
                }
            }
        }

        // ---------- G2: h <- h + W2 t^T (acc = transformed h) ----------
        STAGE(CHB(1, 0, 0), 0);
        STAGE(CHB(1, 1, 0), 1024);
        __syncthreads();
#pragma unroll
        for (int ksp = 0; ksp < 8; ++ksp) {
            const int cur = ksp & 1;
            if (ksp < 7) {
                STAGE(CHB(1, 0, ksp+1), (cur^1)*2048);
                STAGE(CHB(1, 1, ksp+1), (cur^1)*2048 + 1024);
            }
#pragma unroll
            for (int ks2 = 0; ks2 < 2; ++ks2) {
                short8 Bh, Bl;
                ASSEMBLE(tpk, ksp*8 + ks2*4, Bh, Bl);
#pragma unroll
                for (int nt = 0; nt < 8; ++nt) {
                    const int sl = cur*2048 + (nt>>2)*1024 + ks2*512 + (nt&3)*128 + lane;
                    short8 Ah = *(const short8*)&wf[sl];
                    short8 Al = *(const short8*)&wf[sl + 64];
                    MMAC(hr[nt], Ah, Al, Bh, Bl);
                }
            }
            __syncthreads();
        }

        // ---------- norm clip ----------
        {
            float ss = 0.0f;
#pragma unroll
            for (int T = 0; T < 8; ++T)
#pragma unroll
                for (int r = 0; r < 16; ++r) ss += hr[T][r]*hr[T][r];
            ss += __shfl_xor(ss, 32);
            float n = sqrtf(ss);
            float sc = (n > 10.0f) ? (10.0f / (n + 1e-8f)) : 1.0f;
#pragma unroll
            for (int T = 0; T < 8; ++T)
#pragma unroll
                for (int r = 0; r < 16; ++r) hr[T][r] *= sc;
        }
    }

    // ---------- store h_final ----------
#pragma unroll
    for (int T = 0; T < 8; ++T) {
#pragma unroll
        for (int q = 0; q < 4; ++q) {
            float4 v;
            v.x = hr[T][q*4+0]; v.y = hr[T][q*4+1]; v.z = hr[T][q*4+2]; v.w = hr[T][q*4+3];
            *(float4*)&out_h[(size_t)bglob*DIMX + T*32 + q*8 + hl*4] = v;
        }
    }
}

extern "C" void kernel_launch(void* const* d_in, const int* in_sizes, int n_in,
                              void* d_out, int out_size, void* d_ws, size_t ws_size,
                              hipStream_t stream) {
    const float* h0      = (const float*)d_in[0];
    const float* W1      = (const float*)d_in[1];
    const float* b1      = (const float*)d_in[2];
    const float* W2      = (const float*)d_in[3];
    const float* b2      = (const float*)d_in[4];
    const float* anchors = (const float*)d_in[5];
    const int B = in_sizes[0] / DIMX;

    float* out_h     = (float*)d_out;
    float* out_align = out_h + (long long)B * DIMX;
    float* out_div   = out_align + (long long)NL * B * 3;
    float* out_tens  = out_div   + (long long)NL * B * 3;

    u32x4* ws = (u32x4*)d_ws;   // needs 512 KiB

    hipLaunchKernelGGL(wsplit, dim3(128), dim3(256), 0, stream, W1, W2, ws);
    hipLaunchKernelGGL(collapse_mfma, dim3(B / RPB), dim3(512), 0, stream,
                       h0, b1, b2, anchors, ws,
                       out_h, out_align, out_div, out_tens, B);
}

// Round 3
// 1369.348 us; speedup vs baseline: 3.6720x; 3.6720x over previous
//
#include <hip/hip_runtime.h>
#include <math.h>

// CollapseEngine R3: bf16x3 split MFMA 16x16x32, 16 batch rows/wave.
// h state register-resident (64 f32/lane) in phi-permuted layout; the k-axis
// permutation phi (= MFMA D layout of the previous GEMM) is baked into the
// precomputed W fragments, so NO cross-lane data movement is ever needed:
// D-output -> next B-operand is pure in-lane cvt_pk packing.
// phi(ks,G,i) = 32*ks + 16*(i>>2) + 4*G + (i&3),  G = lane>>4.
// State slot s = 8*ks + i  <->  tile mt = s>>2 (=2ks+(i>>2)), reg r = s&3,
// feat = 16*mt + 4*G + r.

#define DIMX 256
#define NL 6

typedef float f32x4 __attribute__((ext_vector_type(4)));
typedef short short8 __attribute__((ext_vector_type(8)));
typedef unsigned int u32x4 __attribute__((ext_vector_type(4)));

// ws granule chunk base: chunk (gemm g, pass, ks) = 1024 granules of 16B
#define CHB(g, pass, ks) ((((g)*2 + (pass))*8 + (ks)) * 1024)

// pack f32 pair -> (hi u32 = 2 bf16 trunc, lo u32 = 2 bf16 residual)
// low half = X0 (even slot), high half = X1 (odd slot). HW-validated in R2.
#define PACKPAIR(X0, X1, HI, LO)                                                 \
    {                                                                            \
        unsigned b0_ = __float_as_uint(X0), b1_ = __float_as_uint(X1);           \
        HI = __builtin_amdgcn_perm(b1_, b0_, 0x07060302u);                       \
        float l0_ = (X0) - __uint_as_float(b0_ & 0xffff0000u);                   \
        float l1_ = (X1) - __uint_as_float(b1_ & 0xffff0000u);                   \
        asm("v_cvt_pk_bf16_f32 %0, %1, %2" : "=v"(LO) : "v"(l0_), "v"(l1_));     \
    }

#define MMAC(ACC, Ah, Al, Bh, Bl)                                                \
    ACC = __builtin_amdgcn_mfma_f32_16x16x32_bf16(Ah, Bh, ACC, 0, 0, 0);         \
    ACC = __builtin_amdgcn_mfma_f32_16x16x32_bf16(Ah, Bl, ACC, 0, 0, 0);         \
    ACC = __builtin_amdgcn_mfma_f32_16x16x32_bf16(Al, Bh, ACC, 0, 0, 0);

// ---------------- W split + phi-ordered fragment precompute ----------------
// granule gi = [g(2)][pass(2)][ks(8)][t8(8)][hl(2)][lane(64)] = 32768 x 16B
// lane ln holds A[m = 16*(pass*8+t8) + (ln&15)][slots (G=ln>>4)*8 + 0..7]
// slot i carries W[m][phi(ks,G,i)]; u32 p = slots (2p, 2p+1).
__global__ void wsplit(const float* __restrict__ W1, const float* __restrict__ W2,
                       u32x4* __restrict__ ws) {
    int gi   = blockIdx.x * 256 + threadIdx.x;      // 0..32767
    int ln   = gi & 63;
    int hl   = (gi >> 6) & 1;
    int t8   = (gi >> 7) & 7;
    int ks   = (gi >> 10) & 7;
    int pass = (gi >> 13) & 1;
    int g    = (gi >> 14) & 1;
    int m    = (pass * 8 + t8) * 16 + (ln & 15);
    int G    = ln >> 4;
    const float* Wg = g ? W2 : W1;
    unsigned o[4];
#pragma unroll
    for (int p = 0; p < 4; ++p) {
        int f = 32 * ks + ((p >> 1) << 4) + 4 * G + ((p & 1) << 1);
        float x0 = Wg[m * DIMX + f];
        float x1 = Wg[m * DIMX + f + 1];
        unsigned b0 = __float_as_uint(x0), b1 = __float_as_uint(x1);
        if (hl == 0) {
            o[p] = __builtin_amdgcn_perm(b1, b0, 0x07060302u);
        } else {
            float l0 = x0 - __uint_as_float(b0 & 0xffff0000u);
            float l1 = x1 - __uint_as_float(b1 & 0xffff0000u);
            unsigned lp;
            asm("v_cvt_pk_bf16_f32 %0, %1, %2" : "=v"(lp) : "v"(l0), "v"(l1));
            o[p] = lp;
        }
    }
    u32x4 out = {o[0], o[1], o[2], o[3]};
    ws[gi] = out;
}

// ---------------- main fused kernel ----------------

// stage one 16KB chunk (1024 granules) into LDS: 512 thr x 2 x 16B
#define STAGE(gIdxBase, ldsSlotBase)                                             \
    {                                                                            \
        _Pragma("unroll")                                                        \
        for (int i_ = 0; i_ < 2; ++i_) {                                         \
            const int off_ = ((w * 2 + i_) << 6);                                \
            __builtin_amdgcn_global_load_lds(                                    \
                (const __attribute__((address_space(1))) void*)(ws + (gIdxBase) + off_ + lane), \
                (__attribute__((address_space(3))) void*)(&wf[(ldsSlotBase) + off_]),           \
                16, 0, 0);                                                       \
        }                                                                        \
    }

__global__ __launch_bounds__(512, 2)
void collapse_mfma16(const float* __restrict__ h0,
                     const float* __restrict__ b1f,
                     const float* __restrict__ b2f,
                     const float* __restrict__ anchors,
                     const u32x4* __restrict__ ws,
                     float* __restrict__ out_h,
                     float* __restrict__ out_align,
                     float* __restrict__ out_div,
                     float* __restrict__ out_tens,
                     int B)
{
    __shared__ __align__(16) u32x4 wf[2048];        // 2 x 16KB W-frag dbuf
    __shared__ __align__(16) float an_reg[3][256];  // normalized anchors, phi-layout
    __shared__ __align__(16) float b1_reg[256];
    __shared__ __align__(16) float b2_reg[256];
    __shared__ float an_inv[3];

    const int tid  = threadIdx.x;
    const int w    = tid >> 6;
    const int lane = tid & 63;
    const int G    = lane >> 4;          // k-octet / D-row group
    const int c    = lane & 15;          // batch col within wave tile
    const int bglob = blockIdx.x * 128 + w * 16 + c;

    // anchor inverse norms (waves 0..2)
    if (w < 3) {
        const float4 av = *(const float4*)&anchors[w * DIMX + lane * 4];
        float ss = av.x * av.x + av.y * av.y + av.z * av.z + av.w * av.w;
#pragma unroll
        for (int m = 1; m < 64; m <<= 1) ss += __shfl_xor(ss, m, 64);
        if (lane == 0) an_inv[w] = 1.0f / fmaxf(sqrtf(ss), 1e-12f);
    }
    __syncthreads();

    // const arrays in phi-layout: idx = Gc*64 + s, feat = 16*(s>>2)+4*Gc+(s&3)
    {
        int idx = tid & 255;
        int Gc = idx >> 6, s = idx & 63;
        int f = 16 * (s >> 2) + 4 * Gc + (s & 3);
        if (tid < 256) {
            b1_reg[idx] = b1f[f];
#pragma unroll
            for (int k = 0; k < 3; ++k)
                an_reg[k][idx] = anchors[k * DIMX + f] * an_inv[k];
        } else {
            b2_reg[idx] = b2f[f];
        }
    }
    __syncthreads();

    // load h0 into phi-layout regs: hr[mt*4+r] = h0[row][16mt+4G+r]
    float hr[64];
#pragma unroll
    for (int mt = 0; mt < 16; ++mt) {
        const float4 v = *(const float4*)&h0[(size_t)bglob * DIMX + 16 * mt + 4 * G];
        hr[mt * 4 + 0] = v.x; hr[mt * 4 + 1] = v.y;
        hr[mt * 4 + 2] = v.z; hr[mt * 4 + 3] = v.w;
    }

#pragma unroll 1
    for (int layer = 0; layer < NL; ++layer) {
        // ---------- stats: p0=|h|^2, dk=h.Ak ; |h-Ak|^2 = p0-2dk+1 ----------
        float p0 = 0, d0 = 0, d1 = 0, d2 = 0;
#pragma unroll
        for (int q = 0; q < 16; ++q) {
            const float4 a0 = *(const float4*)&an_reg[0][G * 64 + q * 4];
            const float4 a1 = *(const float4*)&an_reg[1][G * 64 + q * 4];
            const float4 a2 = *(const float4*)&an_reg[2][G * 64 + q * 4];
            float x;
            x = hr[q*4+0]; p0 += x*x; d0 += x*a0.x; d1 += x*a1.x; d2 += x*a2.x;
            x = hr[q*4+1]; p0 += x*x; d0 += x*a0.y; d1 += x*a1.y; d2 += x*a2.y;
            x = hr[q*4+2]; p0 += x*x; d0 += x*a0.z; d1 += x*a1.z; d2 += x*a2.z;
            x = hr[q*4+3]; p0 += x*x; d0 += x*a0.w; d1 += x*a1.w; d2 += x*a2.w;
        }
        p0 += __shfl_xor(p0, 16); d0 += __shfl_xor(d0, 16);
        d1 += __shfl_xor(d1, 16); d2 += __shfl_xor(d2, 16);
        p0 += __shfl_xor(p0, 32); d0 += __shfl_xor(d0, 32);
        d1 += __shfl_xor(d1, 32); d2 += __shfl_xor(d2, 32);
        const float inv_rn = 1.0f / fmaxf(sqrtf(p0), 1e-12f);
        const float al0 = d0 * inv_rn, al1 = d1 * inv_rn, al2 = d2 * inv_rn;
        const float dv0 = 1.0f - al0, dv1 = 1.0f - al1, dv2 = 1.0f - al2;
        const float c0 = -0.10f * dv0 / fmaxf(sqrtf(fmaxf(p0 - 2.0f*d0 + 1.0f, 0.0f)), 1e-12f);
        const float c1 = -0.10f * dv1 / fmaxf(sqrtf(fmaxf(p0 - 2.0f*d1 + 1.0f, 0.0f)), 1e-12f);
        const float c2 = -0.05f * dv2 / fmaxf(sqrtf(fmaxf(p0 - 2.0f*d2 + 1.0f, 0.0f)), 1e-12f);
        if (G == 0) {
            const long long tb = ((long long)layer * B + bglob) * 3;
            out_align[tb+0] = al0; out_align[tb+1] = al1; out_align[tb+2] = al2;
            out_div[tb+0] = dv0;   out_div[tb+1] = dv1;   out_div[tb+2] = dv2;
            out_tens[tb+0] = dv0*dv0; out_tens[tb+1] = dv1*dv1; out_tens[tb+2] = dv2*dv2;
        }

        // ---------- G1: t = tanh(W1 h + b1), 2 passes of 8 out-tiles ----------
        unsigned tph[32], tpl[32];
#pragma unroll
        for (int pass = 0; pass < 2; ++pass) {
            f32x4 ac[8];
#pragma unroll
            for (int j = 0; j < 8; ++j) ac[j] = (f32x4)(0.0f);

            STAGE(CHB(0, pass, 0), 0);
            __syncthreads();
#pragma unroll
            for (int ks = 0; ks < 8; ++ks) {
                const int cur = ks & 1;
                if (ks < 7) STAGE(CHB(0, pass, ks + 1), (cur ^ 1) * 1024);
                unsigned bh[4], bl[4];
#pragma unroll
                for (int p = 0; p < 4; ++p)
                    PACKPAIR(hr[8*ks + 2*p], hr[8*ks + 2*p + 1], bh[p], bl[p]);
                u32x4 thi = {bh[0], bh[1], bh[2], bh[3]};
                u32x4 tlo = {bl[0], bl[1], bl[2], bl[3]};
                const short8 Bh = __builtin_bit_cast(short8, thi);
                const short8 Bl = __builtin_bit_cast(short8, tlo);
#pragma unroll
                for (int j = 0; j < 8; ++j) {
                    const short8 Ah = __builtin_bit_cast(short8, wf[cur*1024 + j*128 + lane]);
                    const short8 Al = __builtin_bit_cast(short8, wf[cur*1024 + j*128 + 64 + lane]);
                    MMAC(ac[j], Ah, Al, Bh, Bl);
                }
                __syncthreads();
            }
            // tanh + b1, pack into t (phi-layout)
#pragma unroll
            for (int j = 0; j < 8; ++j) {
                const int mt = pass * 8 + j;
                const float4 bq = *(const float4*)&b1_reg[G * 64 + mt * 4];
                float tv[4];
#pragma unroll
                for (int r = 0; r < 4; ++r) {
                    float x = ac[j][r] + ((r==0)?bq.x:(r==1)?bq.y:(r==2)?bq.z:bq.w);
                    float e = __expf(2.0f * x);
                    tv[r] = 1.0f - 2.0f * __builtin_amdgcn_rcpf(e + 1.0f);
                }
                const int ti = 4 * (mt >> 1) + 2 * (mt & 1);
                PACKPAIR(tv[0], tv[1], tph[ti],     tpl[ti]);
                PACKPAIR(tv[2], tv[3], tph[ti + 1], tpl[ti + 1]);
            }
        }

        // ---------- G2: h' = (h + b2 + force) + W2 t, 2 passes ----------
        const float csum = 1.0f + c0 + c1 + c2;
#pragma unroll
        for (int pass = 0; pass < 2; ++pass) {
            f32x4 ac[8];
#pragma unroll
            for (int j = 0; j < 8; ++j) {
                const int mt = pass * 8 + j;
                const float4 a0 = *(const float4*)&an_reg[0][G * 64 + mt * 4];
                const float4 a1 = *(const float4*)&an_reg[1][G * 64 + mt * 4];
                const float4 a2 = *(const float4*)&an_reg[2][G * 64 + mt * 4];
                const float4 bq = *(const float4*)&b2_reg[G * 64 + mt * 4];
                ac[j][0] = hr[mt*4+0]*csum - (c0*a0.x + c1*a1.x + c2*a2.x) + bq.x;
                ac[j][1] = hr[mt*4+1]*csum - (c0*a0.y + c1*a1.y + c2*a2.y) + bq.y;
                ac[j][2] = hr[mt*4+2]*csum - (c0*a0.z + c1*a1.z + c2*a2.z) + bq.z;
                ac[j][3] = hr[mt*4+3]*csum - (c0*a0.w + c1*a1.w + c2*a2.w) + bq.w;
            }
            STAGE(CHB(1, pass, 0), 0);
            __syncthreads();
#pragma unroll
            for (int ks = 0; ks < 8; ++ks) {
                const int cur = ks & 1;
                if (ks < 7) STAGE(CHB(1, pass, ks + 1), (cur ^ 1) * 1024);
                u32x4 thi = {tph[4*ks+0], tph[4*ks+1], tph[4*ks+2], tph[4*ks+3]};
                u32x4 tlo = {tpl[4*ks+0], tpl[4*ks+1], tpl[4*ks+2], tpl[4*ks+3]};
                const short8 Bh = __builtin_bit_cast(short8, thi);
                const short8 Bl = __builtin_bit_cast(short8, tlo);
#pragma unroll
                for (int j = 0; j < 8; ++j) {
                    const short8 Ah = __builtin_bit_cast(short8, wf[cur*1024 + j*128 + lane]);
                    const short8 Al = __builtin_bit_cast(short8, wf[cur*1024 + j*128 + 64 + lane]);
                    MMAC(ac[j], Ah, Al, Bh, Bl);
                }
                __syncthreads();
            }
#pragma unroll
            for (int j = 0; j < 8; ++j) {
                const int mt = pass * 8 + j;
                hr[mt*4+0] = ac[j][0]; hr[mt*4+1] = ac[j][1];
                hr[mt*4+2] = ac[j][2]; hr[mt*4+3] = ac[j][3];
            }
        }

        // ---------- norm clip (in regs) ----------
        {
            float ss = 0.0f;
#pragma unroll
            for (int s = 0; s < 64; ++s) ss += hr[s] * hr[s];
            ss += __shfl_xor(ss, 16);
            ss += __shfl_xor(ss, 32);
            const float n = sqrtf(ss);
            const float sc = (n > 10.0f) ? (10.0f / (n + 1e-8f)) : 1.0f;
#pragma unroll
            for (int s = 0; s < 64; ++s) hr[s] *= sc;
        }
    }

    // ---------- store h_final ----------
#pragma unroll
    for (int mt = 0; mt < 16; ++mt) {
        float4 v;
        v.x = hr[mt*4+0]; v.y = hr[mt*4+1]; v.z = hr[mt*4+2]; v.w = hr[mt*4+3];
        *(float4*)&out_h[(size_t)bglob * DIMX + 16 * mt + 4 * G] = v;
    }
}

extern "C" void kernel_launch(void* const* d_in, const int* in_sizes, int n_in,
                              void* d_out, int out_size, void* d_ws, size_t ws_size,
                              hipStream_t stream) {
    const float* h0      = (const float*)d_in[0];
    const float* W1      = (const float*)d_in[1];
    const float* b1      = (const float*)d_in[2];
    const float* W2      = (const float*)d_in[3];
    const float* b2      = (const float*)d_in[4];
    const float* anchors = (const float*)d_in[5];
    const int B = in_sizes[0] / DIMX;

    float* out_h     = (float*)d_out;
    float* out_align = out_h + (long long)B * DIMX;
    float* out_div   = out_align + (long long)NL * B * 3;
    float* out_tens  = out_div   + (long long)NL * B * 3;

    u32x4* ws = (u32x4*)d_ws;   // 512 KiB

    hipLaunchKernelGGL(wsplit, dim3(128), dim3(256), 0, stream, W1, W2, ws);
    hipLaunchKernelGGL(collapse_mfma16, dim3(B / 128), dim3(512), 0, stream,
                       h0, b1, b2, anchors, ws,
                       out_h, out_align, out_div, out_tens, B);
}